// Round 3
// baseline (217.839 us; speedup 1.0000x reference)
//
#include <hip/hip_runtime.h>

#define POS_DIM 15
#define NLAYERS 32
#define H 16
#define INDIM 124

typedef _Float16 half4 __attribute__((ext_vector_type(4)));
typedef _Float16 half8 __attribute__((ext_vector_type(8)));
typedef float floatx4 __attribute__((ext_vector_type(4)));
typedef float floatx2 __attribute__((ext_vector_type(2)));

// Split-f16 (Ootomo) MFMA: v = hi + lo with hi=f16(v), lo=f16(v-hi); then
// W*h = Whi*hhi + Whi*hlo + Wlo*hhi (drop Wlo*hlo ~ 2^-22 rel).  Master h
// stays fp32.  hT lives in the MFMA D-fragment (m=quad*4+r, n=lane&15),
// which is layout-identical to the next 16x16x16 f16 B-fragment.
// NOTE: features k=124..127 need no zeroing on the B side — the staged
// W1^T A-fragments are zero for k>=124, so their products vanish.
__global__ __launch_bounds__(256) void fractal_kernel(
    const float* __restrict__ z, const float* __restrict__ c,
    const float* __restrict__ W1, const float* __restrict__ b1,
    const float* __restrict__ Ws, const float* __restrict__ bs,
    const float* __restrict__ Wf, const float* __restrict__ bf,
    float* __restrict__ out, int B)
{
    __shared__ half8 lds_w1hi[4 * 64], lds_w1lo[4 * 64];      // layer-1 A frags
    __shared__ half4 lds_whi[NLAYERS * 64], lds_wlo[NLAYERS * 64];
    __shared__ floatx4 lds_bs[NLAYERS * 4];                   // bias frags

    const int tid = threadIdx.x;

    // Stage W1^T hi/lo fragments: A[m=col][k] = W1[k][col], k = t*32 + q*8 + j
    for (int idx = tid; idx < 4 * 64; idx += 256) {
        int t = idx >> 6, lane = idx & 63;
        int q = lane >> 4, col = lane & 15;
        half8 vh, vl;
#pragma unroll
        for (int j = 0; j < 8; ++j) {
            int k = t * 32 + q * 8 + j;
            float w = (k < INDIM) ? W1[k * H + col] : 0.f;
            _Float16 hi = (_Float16)w;
            vh[j] = hi;
            vl[j] = (_Float16)(w - (float)hi);
        }
        lds_w1hi[idx] = vh;
        lds_w1lo[idx] = vl;
    }
    // Stage Ws^T hi/lo fragments: A[m=col][k] = Ws[l][k][col], k = q*4 + j
    for (int idx = tid; idx < NLAYERS * 64; idx += 256) {
        int l = idx >> 6, lane = idx & 63;
        int q = lane >> 4, col = lane & 15;
        half4 vh, vl;
#pragma unroll
        for (int j = 0; j < 4; ++j) {
            float w = Ws[l * H * H + (q * 4 + j) * H + col];
            _Float16 hi = (_Float16)w;
            vh[j] = hi;
            vl[j] = (_Float16)(w - (float)hi);
        }
        lds_whi[idx] = vh;
        lds_wlo[idx] = vl;
    }
    // Stage bias fragments: lds_bs[l*4+q] = bs[l][q*4 .. q*4+3]
    for (int idx = tid; idx < NLAYERS * 4; idx += 256) {
        int l = idx >> 2, q = idx & 3;
        floatx4 v;
#pragma unroll
        for (int j = 0; j < 4; ++j) v[j] = bs[l * H + q * 4 + j];
        lds_bs[idx] = v;
    }
    __syncthreads();

    const int lane = tid & 63;
    const int q = lane >> 4, col = lane & 15;
    const int wave0 = (blockIdx.x * 256 + tid) >> 6;
    const int nwaves = (gridDim.x * 256) >> 6;
    const int ntiles = B >> 4;

    constexpr float C_HI = 0.15915494309189535f;                        // fl(1/2pi)
    constexpr float C_LO = (float)(0.15915494309189535 - (double)C_HI); // residual

    const floatx2* z2 = (const floatx2*)z;
    const floatx2* c2 = (const floatx2*)c;
    const floatx4 bias1 = *(const floatx4*)(b1 + q * 4);
    const floatx4 wf4 = *(const floatx4*)(Wf + q * 4);
    const float bff = bf[0];

    for (int tile = wave0; tile < ntiles; tile += nwaves) {
        const int n = tile * 16 + col;
        floatx2 zz = z2[n], cc = c2[n];
        float xv[4] = {zz.x, zz.y, cc.x, cc.y};

        // two-float x/(2pi): x*2^i exact in fp32, so frac((yh+yl)*2^i) gives
        // an accurate phase for sin(x*2^i) without Payne-Hanek.
        float yh[4], yl[4];
#pragma unroll
        for (int d = 0; d < 4; ++d) {
            yh[d] = xv[d] * C_HI;
            yl[d] = __builtin_fmaf(xv[d], C_HI, -yh[d]) + xv[d] * C_LO;
        }

        floatx4 acc = bias1;
#pragma unroll
        for (int t = 0; t < 4; ++t) {
            // features k = t*32 + q*8 + j: j<4 -> cos(2^(t*4+q-1) x_d),
            // j>=4 -> sin(2^(t*4+q) x_d), d=j&3; t=0,q=0,j<4 -> raw x.
            // k=124..127 (t=3,q=3,j>=4) hit zeroed A columns — value harmless.
            const float sc_cos = __builtin_ldexpf(1.0f, t * 4 + q - 1);
            const float sc_sin = __builtin_ldexpf(1.0f, t * 4 + q);
            half8 bhi, blo;
#pragma unroll
            for (int j = 0; j < 8; ++j) {
                const int d = j & 3;
                const bool is_cos = (j < 4);
                const float sc = is_cos ? sc_cos : sc_sin;
                float tt = yh[d] * sc;                  // exact (sc = 2^i)
                float fr = tt - __builtin_floorf(tt);   // exact (Sterbenz)
                fr = __builtin_fmaf(yl[d], sc, fr);
                if (is_cos) fr += 0.25f;                // exact: fr in [0,1)
                float fv = __builtin_amdgcn_sinf(fr);   // v_sin: sin(2*pi*fr)
                if (t == 0 && is_cos) fv = (q == 0) ? xv[j] : fv;
                _Float16 fh = (_Float16)fv;
                bhi[j] = fh;
                blo[j] = (_Float16)(fv - (float)fh);
            }
            half8 ah = lds_w1hi[t * 64 + lane], al = lds_w1lo[t * 64 + lane];
            acc = __builtin_amdgcn_mfma_f32_16x16x32_f16(ah, bhi, acc, 0, 0, 0);
            acc = __builtin_amdgcn_mfma_f32_16x16x32_f16(ah, blo, acc, 0, 0, 0);
            acc = __builtin_amdgcn_mfma_f32_16x16x32_f16(al, bhi, acc, 0, 0, 0);
        }

        // master h in fp32; leaky(x) = max(x, 0.2x)
        float h0 = fmaxf(acc[0], 0.2f * acc[0]);
        float h1 = fmaxf(acc[1], 0.2f * acc[1]);
        float h2 = fmaxf(acc[2], 0.2f * acc[2]);
        float h3 = fmaxf(acc[3], 0.2f * acc[3]);

#pragma unroll
        for (int l = 0; l < NLAYERS; ++l) {
            half4 hhi, hlo;
            _Float16 a0 = (_Float16)h0, a1 = (_Float16)h1,
                     a2 = (_Float16)h2, a3 = (_Float16)h3;
            hhi[0] = a0; hhi[1] = a1; hhi[2] = a2; hhi[3] = a3;
            hlo[0] = (_Float16)(h0 - (float)a0);
            hlo[1] = (_Float16)(h1 - (float)a1);
            hlo[2] = (_Float16)(h2 - (float)a2);
            hlo[3] = (_Float16)(h3 - (float)a3);
            half4 wh = lds_whi[l * 64 + lane], wl = lds_wlo[l * 64 + lane];
            floatx4 d4 = lds_bs[l * 4 + q];
            d4 = __builtin_amdgcn_mfma_f32_16x16x16f16(wh, hhi, d4, 0, 0, 0);
            d4 = __builtin_amdgcn_mfma_f32_16x16x16f16(wh, hlo, d4, 0, 0, 0);
            d4 = __builtin_amdgcn_mfma_f32_16x16x16f16(wl, hhi, d4, 0, 0, 0);
            h0 += fmaxf(d4[0], 0.2f * d4[0]);
            h1 += fmaxf(d4[1], 0.2f * d4[1]);
            h2 += fmaxf(d4[2], 0.2f * d4[2]);
            h3 += fmaxf(d4[3], 0.2f * d4[3]);
        }

        // out[n] = sum_m h[m] * Wf[m] + bf ; column n spread over 4 quads
        float p = h0 * wf4.x + h1 * wf4.y + h2 * wf4.z + h3 * wf4.w;
        p += __shfl_xor(p, 16, 64);
        p += __shfl_xor(p, 32, 64);
        if (q == 0) out[n] = p + bff;
    }
}

extern "C" void kernel_launch(void* const* d_in, const int* in_sizes, int n_in,
                              void* d_out, int out_size, void* d_ws, size_t ws_size,
                              hipStream_t stream) {
    const float* z  = (const float*)d_in[0];
    const float* c  = (const float*)d_in[1];
    const float* W1 = (const float*)d_in[2];
    const float* b1 = (const float*)d_in[3];
    const float* Ws = (const float*)d_in[4];
    const float* bs = (const float*)d_in[5];
    const float* Wf = (const float*)d_in[6];
    const float* bf = (const float*)d_in[7];
    const int B = in_sizes[0] / 2;  // z is (B,2)

    const int blocks = 2048;  // 8192 waves x 4 tiles = 32768 tiles of 16
    fractal_kernel<<<blocks, 256, 0, stream>>>(z, c, W1, b1, Ws, bs, Wf, bf,
                                               (float*)d_out, B);
}

// Round 5
// 180.543 us; speedup vs baseline: 1.2066x; 1.2066x over previous
//
#include <hip/hip_runtime.h>

#define NLAYERS 32
#define H 16
#define INDIM 124

typedef __fp16 pk16x2 __attribute__((ext_vector_type(2)));   // cvt_pkrtz result
typedef _Float16 half4 __attribute__((ext_vector_type(4)));
typedef _Float16 half8 __attribute__((ext_vector_type(8)));
typedef float floatx4 __attribute__((ext_vector_type(4)));
typedef float floatx2 __attribute__((ext_vector_type(2)));

// Split-f16 MFMA residual MLP.  hT lives in the MFMA D-fragment
// (m=quad*4+r, n=lane&15) == the next 16x16x16 f16 B-fragment layout.
// Two batch tiles are processed per wave iteration (independent MFMA/VALU
// chains, shared weight ds_reads) to hide MFMA latency at low occupancy.
// Feature-side lo term dropped (error ~2e-2 total); W-lo terms kept (free,
// staged in LDS); residual h-lo term kept (h grows large).
__global__ __launch_bounds__(256) void fractal_kernel(
    const float* __restrict__ z, const float* __restrict__ c,
    const float* __restrict__ W1, const float* __restrict__ b1,
    const float* __restrict__ Ws, const float* __restrict__ bs,
    const float* __restrict__ Wf, const float* __restrict__ bf,
    float* __restrict__ out, int B)
{
    __shared__ half8 lds_w1hi[4 * 64], lds_w1lo[4 * 64];      // layer-1 A frags
    __shared__ half4 lds_whi[NLAYERS * 64], lds_wlo[NLAYERS * 64];
    __shared__ floatx4 lds_bs[NLAYERS * 4];                   // bias frags

    const int tid = threadIdx.x;

    // Stage W1^T hi/lo fragments: A[m=col][k] = W1[k][col], k = t*32 + q*8 + j
    for (int idx = tid; idx < 4 * 64; idx += 256) {
        int t = idx >> 6, lane = idx & 63;
        int q = lane >> 4, col = lane & 15;
        half8 vh, vl;
#pragma unroll
        for (int j = 0; j < 8; ++j) {
            int k = t * 32 + q * 8 + j;
            float w = (k < INDIM) ? W1[k * H + col] : 0.f;
            _Float16 hi = (_Float16)w;
            vh[j] = hi;
            vl[j] = (_Float16)(w - (float)hi);
        }
        lds_w1hi[idx] = vh;
        lds_w1lo[idx] = vl;
    }
    // Stage Ws^T hi/lo fragments: A[m=col][k] = Ws[l][k][col], k = q*4 + j
    for (int idx = tid; idx < NLAYERS * 64; idx += 256) {
        int l = idx >> 6, lane = idx & 63;
        int q = lane >> 4, col = lane & 15;
        half4 vh, vl;
#pragma unroll
        for (int j = 0; j < 4; ++j) {
            float w = Ws[l * H * H + (q * 4 + j) * H + col];
            _Float16 hi = (_Float16)w;
            vh[j] = hi;
            vl[j] = (_Float16)(w - (float)hi);
        }
        lds_whi[idx] = vh;
        lds_wlo[idx] = vl;
    }
    for (int idx = tid; idx < NLAYERS * 4; idx += 256) {
        int l = idx >> 2, q = idx & 3;
        floatx4 v;
#pragma unroll
        for (int j = 0; j < 4; ++j) v[j] = bs[l * H + q * 4 + j];
        lds_bs[idx] = v;
    }
    __syncthreads();

    const int lane = tid & 63;
    const int q = lane >> 4, col = lane & 15;
    const int wave0 = (blockIdx.x * 256 + tid) >> 6;
    const int nwaves = (gridDim.x * 256) >> 6;
    const int ntiles = B >> 4;
    const int npair = ntiles >> 1;

    constexpr float C_HI = 0.15915494309189535f;                        // fl(1/2pi)
    constexpr float C_LO = (float)(0.15915494309189535 - (double)C_HI); // residual

    const floatx2* z2 = (const floatx2*)z;
    const floatx2* c2 = (const floatx2*)c;
    const floatx4 bias1 = *(const floatx4*)(b1 + q * 4);
    const floatx4 wf4 = *(const floatx4*)(Wf + q * 4);
    const float bff = bf[0];

    for (int pair = wave0; pair < npair; pair += nwaves) {
        const int n0 = pair * 16 + col;
        const int n1 = (pair + npair) * 16 + col;
        floatx2 za = z2[n0], ca = c2[n0];
        floatx2 zb = z2[n1], cb = c2[n1];
        float xa[4] = {za.x, za.y, ca.x, ca.y};
        float xb[4] = {zb.x, zb.y, cb.x, cb.y};

        // two-float x/(2pi): x*2^i exact in fp32, so frac((yh+yl)*2^i) gives
        // an accurate phase for sin(x*2^i) without Payne-Hanek.
        float yha[4], yla[4], yhb[4], ylb[4];
#pragma unroll
        for (int d = 0; d < 4; ++d) {
            yha[d] = xa[d] * C_HI;
            yla[d] = __builtin_fmaf(xa[d], C_HI, -yha[d]) + xa[d] * C_LO;
            yhb[d] = xb[d] * C_HI;
            ylb[d] = __builtin_fmaf(xb[d], C_HI, -yhb[d]) + xb[d] * C_LO;
        }

        floatx4 acc0 = bias1, acc1 = bias1;
#pragma unroll
        for (int t = 0; t < 4; ++t) {
            // features k = t*32 + q*8 + j: j<4 -> cos(2^(t*4+q-1) x_d),
            // j>=4 -> sin(2^(t*4+q) x_d), d=j&3; t=0,q=0,j<4 -> raw x.
            // k=124..127 hit zeroed A columns — values harmless.
            const float sc_cos = __builtin_ldexpf(1.0f, t * 4 + q - 1);
            const float sc_sin = __builtin_ldexpf(1.0f, t * 4 + q);
            float fva[8], fvb[8];
#pragma unroll
            for (int j = 0; j < 8; ++j) {
                const int d = j & 3;
                const bool is_cos = (j < 4);
                const float sc = is_cos ? sc_cos : sc_sin;
                float ta = yha[d] * sc;                 // exact (sc = 2^i)
                float fa = ta - __builtin_floorf(ta);
                fa = __builtin_fmaf(yla[d], sc, fa);
                if (is_cos) fa += 0.25f;                // cos = sin(+1/4 rev)
                fva[j] = __builtin_amdgcn_sinf(fa);
                float tb = yhb[d] * sc;
                float fb = tb - __builtin_floorf(tb);
                fb = __builtin_fmaf(ylb[d], sc, fb);
                if (is_cos) fb += 0.25f;
                fvb[j] = __builtin_amdgcn_sinf(fb);
                if (t == 0 && is_cos && q == 0) { fva[j] = xa[j]; fvb[j] = xb[j]; }
            }
            half8 bh0, bh1;
#pragma unroll
            for (int p = 0; p < 4; ++p) {
                pk16x2 pa = __builtin_amdgcn_cvt_pkrtz(fva[2 * p], fva[2 * p + 1]);
                pk16x2 pb = __builtin_amdgcn_cvt_pkrtz(fvb[2 * p], fvb[2 * p + 1]);
                bh0[2 * p] = (_Float16)pa[0]; bh0[2 * p + 1] = (_Float16)pa[1];
                bh1[2 * p] = (_Float16)pb[0]; bh1[2 * p + 1] = (_Float16)pb[1];
            }
            half8 ah = lds_w1hi[t * 64 + lane], al = lds_w1lo[t * 64 + lane];
            acc0 = __builtin_amdgcn_mfma_f32_16x16x32_f16(ah, bh0, acc0, 0, 0, 0);
            acc1 = __builtin_amdgcn_mfma_f32_16x16x32_f16(ah, bh1, acc1, 0, 0, 0);
            acc0 = __builtin_amdgcn_mfma_f32_16x16x32_f16(al, bh0, acc0, 0, 0, 0);
            acc1 = __builtin_amdgcn_mfma_f32_16x16x32_f16(al, bh1, acc1, 0, 0, 0);
        }

        // master h in fp32; leaky(x) = max(x, 0.2x)
        float ha0 = fmaxf(acc0[0], 0.2f * acc0[0]);
        float ha1 = fmaxf(acc0[1], 0.2f * acc0[1]);
        float ha2 = fmaxf(acc0[2], 0.2f * acc0[2]);
        float ha3 = fmaxf(acc0[3], 0.2f * acc0[3]);
        float hb0 = fmaxf(acc1[0], 0.2f * acc1[0]);
        float hb1 = fmaxf(acc1[1], 0.2f * acc1[1]);
        float hb2 = fmaxf(acc1[2], 0.2f * acc1[2]);
        float hb3 = fmaxf(acc1[3], 0.2f * acc1[3]);

#pragma unroll
        for (int l = 0; l < NLAYERS; ++l) {
            half4 wh = lds_whi[l * 64 + lane], wl = lds_wlo[l * 64 + lane];
            floatx4 bias = lds_bs[l * 4 + q];

            pk16x2 pa01 = __builtin_amdgcn_cvt_pkrtz(ha0, ha1);
            pk16x2 pa23 = __builtin_amdgcn_cvt_pkrtz(ha2, ha3);
            pk16x2 pb01 = __builtin_amdgcn_cvt_pkrtz(hb0, hb1);
            pk16x2 pb23 = __builtin_amdgcn_cvt_pkrtz(hb2, hb3);
            half4 hhi0, hhi1;
            hhi0[0] = (_Float16)pa01[0]; hhi0[1] = (_Float16)pa01[1];
            hhi0[2] = (_Float16)pa23[0]; hhi0[3] = (_Float16)pa23[1];
            hhi1[0] = (_Float16)pb01[0]; hhi1[1] = (_Float16)pb01[1];
            hhi1[2] = (_Float16)pb23[0]; hhi1[3] = (_Float16)pb23[1];

            floatx4 d0 = __builtin_amdgcn_mfma_f32_16x16x16f16(wh, hhi0, bias, 0, 0, 0);
            floatx4 d1 = __builtin_amdgcn_mfma_f32_16x16x16f16(wh, hhi1, bias, 0, 0, 0);
            d0 = __builtin_amdgcn_mfma_f32_16x16x16f16(wl, hhi0, d0, 0, 0, 0);
            d1 = __builtin_amdgcn_mfma_f32_16x16x16f16(wl, hhi1, d1, 0, 0, 0);

            pk16x2 la01 = __builtin_amdgcn_cvt_pkrtz(ha0 - (float)hhi0[0],
                                                     ha1 - (float)hhi0[1]);
            pk16x2 la23 = __builtin_amdgcn_cvt_pkrtz(ha2 - (float)hhi0[2],
                                                     ha3 - (float)hhi0[3]);
            pk16x2 lb01 = __builtin_amdgcn_cvt_pkrtz(hb0 - (float)hhi1[0],
                                                     hb1 - (float)hhi1[1]);
            pk16x2 lb23 = __builtin_amdgcn_cvt_pkrtz(hb2 - (float)hhi1[2],
                                                     hb3 - (float)hhi1[3]);
            half4 hlo0, hlo1;
            hlo0[0] = (_Float16)la01[0]; hlo0[1] = (_Float16)la01[1];
            hlo0[2] = (_Float16)la23[0]; hlo0[3] = (_Float16)la23[1];
            hlo1[0] = (_Float16)lb01[0]; hlo1[1] = (_Float16)lb01[1];
            hlo1[2] = (_Float16)lb23[0]; hlo1[3] = (_Float16)lb23[1];

            d0 = __builtin_amdgcn_mfma_f32_16x16x16f16(wh, hlo0, d0, 0, 0, 0);
            d1 = __builtin_amdgcn_mfma_f32_16x16x16f16(wh, hlo1, d1, 0, 0, 0);

            ha0 += fmaxf(d0[0], 0.2f * d0[0]);
            ha1 += fmaxf(d0[1], 0.2f * d0[1]);
            ha2 += fmaxf(d0[2], 0.2f * d0[2]);
            ha3 += fmaxf(d0[3], 0.2f * d0[3]);
            hb0 += fmaxf(d1[0], 0.2f * d1[0]);
            hb1 += fmaxf(d1[1], 0.2f * d1[1]);
            hb2 += fmaxf(d1[2], 0.2f * d1[2]);
            hb3 += fmaxf(d1[3], 0.2f * d1[3]);
        }

        // out[n] = sum_m h[m] * Wf[m] + bf ; column n spread over 4 quads
        float p0 = ha0 * wf4.x + ha1 * wf4.y + ha2 * wf4.z + ha3 * wf4.w;
        float p1 = hb0 * wf4.x + hb1 * wf4.y + hb2 * wf4.z + hb3 * wf4.w;
        p0 += __shfl_xor(p0, 16, 64);
        p0 += __shfl_xor(p0, 32, 64);
        p1 += __shfl_xor(p1, 16, 64);
        p1 += __shfl_xor(p1, 32, 64);
        if (q == 0) { out[n0] = p0 + bff; out[n1] = p1 + bff; }
    }
}

extern "C" void kernel_launch(void* const* d_in, const int* in_sizes, int n_in,
                              void* d_out, int out_size, void* d_ws, size_t ws_size,
                              hipStream_t stream) {
    const float* z  = (const float*)d_in[0];
    const float* c  = (const float*)d_in[1];
    const float* W1 = (const float*)d_in[2];
    const float* b1 = (const float*)d_in[3];
    const float* Ws = (const float*)d_in[4];
    const float* bs = (const float*)d_in[5];
    const float* Wf = (const float*)d_in[6];
    const float* bf = (const float*)d_in[7];
    const int B = in_sizes[0] / 2;  // z is (B,2)

    const int blocks = 2048;  // 8192 waves x 2 pair-iters x 2 tiles = 32768 tiles
    fractal_kernel<<<blocks, 256, 0, stream>>>(z, c, W1, b1, Ws, bs, Wf, bf,
                                               (float*)d_out, B);
}

// Round 7
// 138.241 us; speedup vs baseline: 1.5758x; 1.3060x over previous
//
#include <hip/hip_runtime.h>

#define NLAYERS 32
#define H 16
#define INDIM 124

typedef __fp16 pk16x2 __attribute__((ext_vector_type(2)));   // cvt_pkrtz result
typedef _Float16 half4 __attribute__((ext_vector_type(4)));
typedef _Float16 half8 __attribute__((ext_vector_type(8)));
typedef float floatx4 __attribute__((ext_vector_type(4)));
typedef float floatx2 __attribute__((ext_vector_type(2)));
typedef int intx2 __attribute__((ext_vector_type(2)));
typedef int intx4 __attribute__((ext_vector_type(4)));

static __device__ __forceinline__ half4 mk_half4(pk16x2 a, pk16x2 b) {
    intx2 v;
    v.x = __builtin_bit_cast(int, a);
    v.y = __builtin_bit_cast(int, b);
    return __builtin_bit_cast(half4, v);
}
static __device__ __forceinline__ half8 mk_half8(pk16x2 a, pk16x2 b,
                                                 pk16x2 c, pk16x2 d) {
    intx4 v;
    v.x = __builtin_bit_cast(int, a);
    v.y = __builtin_bit_cast(int, b);
    v.z = __builtin_bit_cast(int, c);
    v.w = __builtin_bit_cast(int, d);
    return __builtin_bit_cast(half8, v);
}

// Split-f16 MFMA residual MLP.  hT lives in the MFMA D-fragment
// (m=quad*4+r, n=lane&15) == the next MFMA's B-fragment layout.
// Per residual layer: d = MFMA16(WThi, hhi, bias) then one K=32 correction
// MFMA with A' = column-interleaved [WThi | WTlo] (staged in LDS) and
// B' = {hlo[0:4], hhi[0:4]} — merging Whi*hlo + Wlo*hhi into one MFMA.
// leaky(x) = 0.6x + 0.4|x| -> two FMAs (|x| is a free modifier).
// hlo = h - (h & 0xFFFFE000)  ==  h - float(f16_rtz(h)) for normal h.
// 4 batch tiles per wave: independent MFMA/VALU chains share weight reads.
__global__ __launch_bounds__(256) void fractal_kernel(
    const float* __restrict__ z, const float* __restrict__ c,
    const float* __restrict__ W1, const float* __restrict__ b1,
    const float* __restrict__ Ws, const float* __restrict__ bs,
    const float* __restrict__ Wf, const float* __restrict__ bf,
    float* __restrict__ out, int B)
{
    __shared__ half8 lds_w1hi[4 * 64], lds_w1lo[4 * 64];  // layer-1 A frags
    __shared__ half4 lds_whi[NLAYERS * 64];               // residual hi A frags
    __shared__ half8 lds_wc[NLAYERS * 64];                // correction A' frags
    __shared__ floatx4 lds_bs[NLAYERS * 4];               // bias frags

    const int tid = threadIdx.x;

    // Stage W1^T hi/lo fragments: A[m=col][k] = W1[k][col], k = t*32 + q*8 + j
    for (int idx = tid; idx < 4 * 64; idx += 256) {
        int t = idx >> 6, lane = idx & 63;
        int q = lane >> 4, col = lane & 15;
        half8 vh, vl;
#pragma unroll
        for (int j = 0; j < 8; ++j) {
            int k = t * 32 + q * 8 + j;
            float w = (k < INDIM) ? W1[k * H + col] : 0.f;
            _Float16 hi = (_Float16)w;
            vh[j] = hi;
            vl[j] = (_Float16)(w - (float)hi);
        }
        lds_w1hi[idx] = vh;
        lds_w1lo[idx] = vl;
    }
    // Stage residual-layer fragments.
    // whi: A[m=col][k=q*4+j] = hi(Ws[l][q*4+j][col]).
    // wc (K=32): A'[m][8q+j] = j<4 ? hi(Ws[l][4q+j][m]) : lo(Ws[l][4q+j-4][m])
    for (int idx = tid; idx < NLAYERS * 64; idx += 256) {
        int l = idx >> 6, lane = idx & 63;
        int q = lane >> 4, col = lane & 15;
        half4 vh;
        half8 vc;
#pragma unroll
        for (int j = 0; j < 4; ++j) {
            float w = Ws[l * H * H + (q * 4 + j) * H + col];
            _Float16 hi = (_Float16)w;
            vh[j] = hi;
            vc[j] = hi;                              // slots j<4 pair with hlo
            vc[j + 4] = (_Float16)(w - (float)hi);   // slots j>=4 pair with hhi
        }
        lds_whi[idx] = vh;
        lds_wc[idx] = vc;
    }
    for (int idx = tid; idx < NLAYERS * 4; idx += 256) {
        int l = idx >> 2, q = idx & 3;
        floatx4 v;
#pragma unroll
        for (int j = 0; j < 4; ++j) v[j] = bs[l * H + q * 4 + j];
        lds_bs[idx] = v;
    }
    __syncthreads();

    const int lane = tid & 63;
    const int q = lane >> 4, col = lane & 15;
    const int wave = (blockIdx.x * 256 + tid) >> 6;
    const int nwaves = (gridDim.x * 256) >> 6;   // 8192
    const int stride16 = nwaves * 16;            // batch stride between tiles

    constexpr float C_HI = 0.15915494309189535f;                        // fl(1/2pi)
    constexpr float C_LO = (float)(0.15915494309189535 - (double)C_HI); // residual

    const floatx2* z2 = (const floatx2*)z;
    const floatx2* c2 = (const floatx2*)c;
    const floatx4 bias1 = *(const floatx4*)(b1 + q * 4);
    const floatx4 wf4 = *(const floatx4*)(Wf + q * 4);
    const float bff = bf[0];

    const int n0 = wave * 16 + col;
    float h[4][4];   // h[i][r]: master fp32 hidden state for tile i

    // ---- Layer 1: positional encoding + Dense(124->16) per tile ----
#pragma unroll
    for (int i = 0; i < 4; ++i) {
        const int n = n0 + i * stride16;
        floatx2 zz = z2[n], cc = c2[n];
        float xv[4] = {zz.x, zz.y, cc.x, cc.y};

        // two-float x/(2pi): x*2^i exact in fp32, so frac((yh+yl)*2^i) gives
        // an accurate phase for sin(x*2^i) without Payne-Hanek.
        float yh[4], yl[4];
#pragma unroll
        for (int d = 0; d < 4; ++d) {
            yh[d] = xv[d] * C_HI;
            yl[d] = __builtin_fmaf(xv[d], C_HI, -yh[d]) + xv[d] * C_LO;
        }

        floatx4 acc = bias1;
#pragma unroll
        for (int t = 0; t < 4; ++t) {
            // features k = t*32 + q*8 + j: j<4 -> cos(2^(t*4+q-1) x_d),
            // j>=4 -> sin(2^(t*4+q) x_d), d=j&3; t=0,q=0,j<4 -> raw x.
            // k=124..127 hit zeroed A columns — values harmless.
            const float sc_cos = __builtin_ldexpf(1.0f, t * 4 + q - 1);
            const float sc_sin = __builtin_ldexpf(1.0f, t * 4 + q);
            float fv[8];
#pragma unroll
            for (int j = 0; j < 8; ++j) {
                const int d = j & 3;
                const bool is_cos = (j < 4);
                const float sc = is_cos ? sc_cos : sc_sin;
                float fr = __builtin_amdgcn_fractf(yh[d] * sc);  // v_fract_f32
                fr = __builtin_fmaf(yl[d], sc, fr);
                if (is_cos) fr += 0.25f;                   // cos = sin(+1/4 rev)
                fv[j] = __builtin_amdgcn_sinf(fr);
                if (t == 0 && is_cos && q == 0) fv[j] = xv[j];
            }
            half8 bh = mk_half8(__builtin_amdgcn_cvt_pkrtz(fv[0], fv[1]),
                                __builtin_amdgcn_cvt_pkrtz(fv[2], fv[3]),
                                __builtin_amdgcn_cvt_pkrtz(fv[4], fv[5]),
                                __builtin_amdgcn_cvt_pkrtz(fv[6], fv[7]));
            half8 ah = lds_w1hi[t * 64 + lane], al = lds_w1lo[t * 64 + lane];
            acc = __builtin_amdgcn_mfma_f32_16x16x32_f16(ah, bh, acc, 0, 0, 0);
            acc = __builtin_amdgcn_mfma_f32_16x16x32_f16(al, bh, acc, 0, 0, 0);
        }
#pragma unroll
        for (int r = 0; r < 4; ++r)
            h[i][r] = fmaxf(acc[r], 0.2f * acc[r]);
    }

    // ---- 32 residual layers, 4 tiles interleaved ----
#pragma unroll
    for (int l = 0; l < NLAYERS; ++l) {
        half4 wh = lds_whi[l * 64 + lane];
        half8 wc = lds_wc[l * 64 + lane];
        floatx4 bias = lds_bs[l * 4 + q];

        floatx4 d4[4];
#pragma unroll
        for (int i = 0; i < 4; ++i) {
            // hi = f16_rtz(h); float(hi) == h & 0xFFFFE000 for normal h.
            half4 hhi = mk_half4(__builtin_amdgcn_cvt_pkrtz(h[i][0], h[i][1]),
                                 __builtin_amdgcn_cvt_pkrtz(h[i][2], h[i][3]));
            float lo[4];
#pragma unroll
            for (int r = 0; r < 4; ++r) {
                unsigned u = __builtin_bit_cast(unsigned, h[i][r]) & 0xFFFFE000u;
                lo[r] = h[i][r] - __builtin_bit_cast(float, u);
            }
            intx2 hbits = __builtin_bit_cast(intx2, hhi);
            half8 bp = mk_half8(__builtin_amdgcn_cvt_pkrtz(lo[0], lo[1]),
                                __builtin_amdgcn_cvt_pkrtz(lo[2], lo[3]),
                                __builtin_bit_cast(pk16x2, hbits.x),
                                __builtin_bit_cast(pk16x2, hbits.y));
            floatx4 d = __builtin_amdgcn_mfma_f32_16x16x16f16(wh, hhi, bias, 0, 0, 0);
            d = __builtin_amdgcn_mfma_f32_16x16x32_f16(wc, bp, d, 0, 0, 0);
            d4[i] = d;
        }
#pragma unroll
        for (int i = 0; i < 4; ++i) {
#pragma unroll
            for (int r = 0; r < 4; ++r) {
                // h += leaky(d) = 0.6d + 0.4|d|
                h[i][r] = __builtin_fmaf(0.6f, d4[i][r], h[i][r]);
                h[i][r] = __builtin_fmaf(0.4f, __builtin_fabsf(d4[i][r]), h[i][r]);
            }
        }
    }

    // ---- Final Dense(16->1): column n spread over 4 quads ----
#pragma unroll
    for (int i = 0; i < 4; ++i) {
        float p = h[i][0] * wf4.x;
        p = __builtin_fmaf(h[i][1], wf4.y, p);
        p = __builtin_fmaf(h[i][2], wf4.z, p);
        p = __builtin_fmaf(h[i][3], wf4.w, p);
        p += __shfl_xor(p, 16, 64);
        p += __shfl_xor(p, 32, 64);
        if (q == 0) out[n0 + i * stride16] = p + bff;
    }
}

extern "C" void kernel_launch(void* const* d_in, const int* in_sizes, int n_in,
                              void* d_out, int out_size, void* d_ws, size_t ws_size,
                              hipStream_t stream) {
    const float* z  = (const float*)d_in[0];
    const float* c  = (const float*)d_in[1];
    const float* W1 = (const float*)d_in[2];
    const float* b1 = (const float*)d_in[3];
    const float* Ws = (const float*)d_in[4];
    const float* bs = (const float*)d_in[5];
    const float* Wf = (const float*)d_in[6];
    const float* bf = (const float*)d_in[7];
    const int B = in_sizes[0] / 2;  // z is (B,2)

    const int blocks = 2048;  // 8192 waves x 4 tiles x 16 = 524288 samples
    fractal_kernel<<<blocks, 256, 0, stream>>>(z, c, W1, b1, Ws, bs, Wf, bf,
                                               (float*)d_out, B);
}

// Round 8
// 129.511 us; speedup vs baseline: 1.6820x; 1.0674x over previous
//
#include <hip/hip_runtime.h>

#define NLAYERS 32
#define H 16
#define INDIM 124

typedef __fp16 pk16x2 __attribute__((ext_vector_type(2)));   // cvt_pkrtz result
typedef _Float16 half4 __attribute__((ext_vector_type(4)));
typedef _Float16 half8 __attribute__((ext_vector_type(8)));
typedef float floatx4 __attribute__((ext_vector_type(4)));
typedef float floatx2 __attribute__((ext_vector_type(2)));
typedef int intx2 __attribute__((ext_vector_type(2)));
typedef int intx4 __attribute__((ext_vector_type(4)));

static __device__ __forceinline__ half4 mk_half4(pk16x2 a, pk16x2 b) {
    intx2 v;
    v.x = __builtin_bit_cast(int, a);
    v.y = __builtin_bit_cast(int, b);
    return __builtin_bit_cast(half4, v);
}
static __device__ __forceinline__ half8 mk_half8(pk16x2 a, pk16x2 b,
                                                 pk16x2 c, pk16x2 d) {
    intx4 v;
    v.x = __builtin_bit_cast(int, a);
    v.y = __builtin_bit_cast(int, b);
    v.z = __builtin_bit_cast(int, c);
    v.w = __builtin_bit_cast(int, d);
    return __builtin_bit_cast(half8, v);
}
static __device__ __forceinline__ half4 low_half(half8 v) {
    intx4 i = __builtin_bit_cast(intx4, v);
    intx2 r; r.x = i.x; r.y = i.y;
    return __builtin_bit_cast(half4, r);
}

// Split-f16 MFMA residual MLP.  hT lives in the MFMA D-fragment
// (m=quad*4+r, n=lane&15) == the next MFMA's B-fragment layout.
// Per residual layer: d = MFMA16(wc.lo, hhi, bias) then one K=32 correction
// MFMA with A' = column-interleaved [WThi | WTlo] (lds_wc) and
// B' = {hlo[0:4], hhi[0:4]} — merging Whi*hlo + Wlo*hhi into one MFMA.
// The K=16 hi A-operand is the LOW HALF of wc — no separate LDS array.
// leaky(x) = 0.6x + 0.4|x| -> two FMAs (|x| is a free src modifier).
// hlo = h - (h & 0xFFFFE000)  ==  h - float(f16_rtz(h)) for normal h.
// 4 batch tiles per wave share all weight reads.
// LDS = 32K (wc) + 4K (w1hi) + 2K (bias) = 38912 B -> 4 blocks/CU.
__global__ __launch_bounds__(256, 4) void fractal_kernel(
    const float* __restrict__ z, const float* __restrict__ c,
    const float* __restrict__ W1, const float* __restrict__ b1,
    const float* __restrict__ Ws, const float* __restrict__ bs,
    const float* __restrict__ Wf, const float* __restrict__ bf,
    float* __restrict__ out, int B)
{
    __shared__ half8 lds_w1hi[4 * 64];       // layer-1 hi A frags
    __shared__ half8 lds_wc[NLAYERS * 64];   // correction A' frags (hi|lo)
    __shared__ floatx4 lds_bs[NLAYERS * 4];  // bias frags

    const int tid = threadIdx.x;
    const int lane = tid & 63;
    const int q = lane >> 4, col = lane & 15;

    // Stage W1^T hi fragments: A[m=col][k] = W1[k][col], k = t*32 + q*8 + j.
    // 4*64 = 256 entries: one per thread.
    {
        int t = tid >> 6, sl = tid & 63;
        int sq = sl >> 4, scol = sl & 15;
        half8 vh;
#pragma unroll
        for (int j = 0; j < 8; ++j) {
            int k = t * 32 + sq * 8 + j;
            float w = (k < INDIM) ? W1[k * H + scol] : 0.f;
            vh[j] = (_Float16)w;
        }
        lds_w1hi[tid] = vh;
    }
    // Stage correction fragments:
    // wc (K=32): A'[m][8q+j] = j<4 ? hi(Ws[l][4q+j][m]) : lo(Ws[l][4q+j-4][m])
    for (int idx = tid; idx < NLAYERS * 64; idx += 256) {
        int l = idx >> 6, sl = idx & 63;
        int sq = sl >> 4, scol = sl & 15;
        half8 vc;
#pragma unroll
        for (int j = 0; j < 4; ++j) {
            float w = Ws[l * H * H + (sq * 4 + j) * H + scol];
            _Float16 hi = (_Float16)w;
            vc[j] = hi;                              // slots j<4: hi (pairs hlo)
            vc[j + 4] = (_Float16)(w - (float)hi);   // slots j>=4: lo (pairs hhi)
        }
        lds_wc[idx] = vc;
    }
    for (int idx = tid; idx < NLAYERS * 4; idx += 256) {
        int l = idx >> 2, sq = idx & 3;
        floatx4 v;
#pragma unroll
        for (int j = 0; j < 4; ++j) v[j] = bs[l * H + sq * 4 + j];
        lds_bs[idx] = v;
    }

    // Layer-1 LO fragments live in registers (own lane's fragment only).
    half8 w1lo[4];
#pragma unroll
    for (int t = 0; t < 4; ++t) {
#pragma unroll
        for (int j = 0; j < 8; ++j) {
            int k = t * 32 + q * 8 + j;
            float w = (k < INDIM) ? W1[k * H + col] : 0.f;
            _Float16 hi = (_Float16)w;
            w1lo[t][j] = (_Float16)(w - (float)hi);
        }
    }
    __syncthreads();

    const int wave = (blockIdx.x * 256 + tid) >> 6;
    const int nwaves = (gridDim.x * 256) >> 6;   // 8192
    const int stride16 = nwaves * 16;            // batch stride between tiles

    constexpr float C_HI = 0.15915494309189535f;                        // fl(1/2pi)
    constexpr float C_LO = (float)(0.15915494309189535 - (double)C_HI); // residual

    const floatx2* z2 = (const floatx2*)z;
    const floatx2* c2 = (const floatx2*)c;
    const floatx4 bias1 = *(const floatx4*)(b1 + q * 4);
    const floatx4 wf4 = *(const floatx4*)(Wf + q * 4);
    const float bff = bf[0];

    const int n0 = wave * 16 + col;
    float h[4][4];   // h[i][r]: master fp32 hidden state for tile i

    // ---- Layer 1: positional encoding + Dense(124->16) per tile ----
#pragma unroll
    for (int i = 0; i < 4; ++i) {
        const int n = n0 + i * stride16;
        floatx2 zz = z2[n], cc = c2[n];
        float xv[4] = {zz.x, zz.y, cc.x, cc.y};

        // two-float x/(2pi): x*2^i exact in fp32, so frac((yh+yl)*2^i) gives
        // an accurate phase for sin(x*2^i) without Payne-Hanek.
        float yh[4], yl[4];
#pragma unroll
        for (int d = 0; d < 4; ++d) {
            yh[d] = xv[d] * C_HI;
            yl[d] = __builtin_fmaf(xv[d], C_HI, -yh[d]) + xv[d] * C_LO;
        }

        floatx4 acc = bias1;
#pragma unroll
        for (int t = 0; t < 4; ++t) {
            // features k = t*32 + q*8 + j: j<4 -> cos(2^(t*4+q-1) x_d),
            // j>=4 -> sin(2^(t*4+q) x_d), d=j&3; t=0,q=0,j<4 -> raw x.
            // k=124..127 hit zeroed A columns — values harmless.
            const float sc_cos = __builtin_ldexpf(1.0f, t * 4 + q - 1);
            const float sc_sin = __builtin_ldexpf(1.0f, t * 4 + q);
            float fv[8];
#pragma unroll
            for (int j = 0; j < 8; ++j) {
                const int d = j & 3;
                const bool is_cos = (j < 4);
                const float sc = is_cos ? sc_cos : sc_sin;
                float fr = __builtin_amdgcn_fractf(yh[d] * sc);  // exact
                fr = __builtin_fmaf(yl[d], sc, fr);
                if (is_cos) fr += 0.25f;                   // cos = sin(+1/4 rev)
                fv[j] = __builtin_amdgcn_sinf(fr);
                if (t == 0 && is_cos && q == 0) fv[j] = xv[j];
            }
            half8 bh = mk_half8(__builtin_amdgcn_cvt_pkrtz(fv[0], fv[1]),
                                __builtin_amdgcn_cvt_pkrtz(fv[2], fv[3]),
                                __builtin_amdgcn_cvt_pkrtz(fv[4], fv[5]),
                                __builtin_amdgcn_cvt_pkrtz(fv[6], fv[7]));
            half8 ah = lds_w1hi[t * 64 + lane];
            acc = __builtin_amdgcn_mfma_f32_16x16x32_f16(ah, bh, acc, 0, 0, 0);
            acc = __builtin_amdgcn_mfma_f32_16x16x32_f16(w1lo[t], bh, acc, 0, 0, 0);
        }
#pragma unroll
        for (int r = 0; r < 4; ++r)
            h[i][r] = fmaxf(acc[r], 0.2f * acc[r]);
    }

    // ---- 32 residual layers, 4 tiles interleaved ----
#pragma unroll
    for (int l = 0; l < NLAYERS; ++l) {
        half8 wc = lds_wc[l * 64 + lane];
        half4 wh = low_half(wc);          // == hi(Ws^T) fragment, free extract
        floatx4 bias = lds_bs[l * 4 + q];

        floatx4 d4[4];
#pragma unroll
        for (int i = 0; i < 4; ++i) {
            // hi = f16_rtz(h); float(hi) == h & 0xFFFFE000 for normal h.
            half4 hhi = mk_half4(__builtin_amdgcn_cvt_pkrtz(h[i][0], h[i][1]),
                                 __builtin_amdgcn_cvt_pkrtz(h[i][2], h[i][3]));
            float lo[4];
#pragma unroll
            for (int r = 0; r < 4; ++r) {
                unsigned u = __builtin_bit_cast(unsigned, h[i][r]) & 0xFFFFE000u;
                lo[r] = h[i][r] - __builtin_bit_cast(float, u);
            }
            intx2 hbits = __builtin_bit_cast(intx2, hhi);
            half8 bp = mk_half8(__builtin_amdgcn_cvt_pkrtz(lo[0], lo[1]),
                                __builtin_amdgcn_cvt_pkrtz(lo[2], lo[3]),
                                __builtin_bit_cast(pk16x2, hbits.x),
                                __builtin_bit_cast(pk16x2, hbits.y));
            floatx4 d = __builtin_amdgcn_mfma_f32_16x16x16f16(wh, hhi, bias, 0, 0, 0);
            d = __builtin_amdgcn_mfma_f32_16x16x32_f16(wc, bp, d, 0, 0, 0);
            d4[i] = d;
        }
#pragma unroll
        for (int i = 0; i < 4; ++i) {
#pragma unroll
            for (int r = 0; r < 4; ++r) {
                // h += leaky(d) = 0.6d + 0.4|d|
                h[i][r] = __builtin_fmaf(0.6f, d4[i][r], h[i][r]);
                h[i][r] = __builtin_fmaf(0.4f, __builtin_fabsf(d4[i][r]), h[i][r]);
            }
        }
    }

    // ---- Final Dense(16->1): column n spread over 4 quads ----
#pragma unroll
    for (int i = 0; i < 4; ++i) {
        float p = h[i][0] * wf4.x;
        p = __builtin_fmaf(h[i][1], wf4.y, p);
        p = __builtin_fmaf(h[i][2], wf4.z, p);
        p = __builtin_fmaf(h[i][3], wf4.w, p);
        p += __shfl_xor(p, 16, 64);
        p += __shfl_xor(p, 32, 64);
        if (q == 0) out[n0 + i * stride16] = p + bff;
    }
}

extern "C" void kernel_launch(void* const* d_in, const int* in_sizes, int n_in,
                              void* d_out, int out_size, void* d_ws, size_t ws_size,
                              hipStream_t stream) {
    const float* z  = (const float*)d_in[0];
    const float* c  = (const float*)d_in[1];
    const float* W1 = (const float*)d_in[2];
    const float* b1 = (const float*)d_in[3];
    const float* Ws = (const float*)d_in[4];
    const float* bs = (const float*)d_in[5];
    const float* Wf = (const float*)d_in[6];
    const float* bf = (const float*)d_in[7];
    const int B = in_sizes[0] / 2;  // z is (B,2)

    const int blocks = 2048;  // 8192 waves x 4 tiles x 16 = 524288 samples
    fractal_kernel<<<blocks, 256, 0, stream>>>(z, c, W1, b1, Ws, bs, Wf, bf,
                                               (float*)d_out, B);
}

// Round 9
// 127.407 us; speedup vs baseline: 1.7098x; 1.0165x over previous
//
#include <hip/hip_runtime.h>

#define NLAYERS 32
#define H 16
#define INDIM 124

typedef __fp16 pk16x2 __attribute__((ext_vector_type(2)));   // cvt_pkrtz result
typedef _Float16 half4 __attribute__((ext_vector_type(4)));
typedef _Float16 half8 __attribute__((ext_vector_type(8)));
typedef float floatx4 __attribute__((ext_vector_type(4)));
typedef float floatx2 __attribute__((ext_vector_type(2)));
typedef int intx2 __attribute__((ext_vector_type(2)));
typedef int intx4 __attribute__((ext_vector_type(4)));

static __device__ __forceinline__ half4 mk_half4(pk16x2 a, pk16x2 b) {
    intx2 v;
    v.x = __builtin_bit_cast(int, a);
    v.y = __builtin_bit_cast(int, b);
    return __builtin_bit_cast(half4, v);
}
static __device__ __forceinline__ half8 mk_half8(pk16x2 a, pk16x2 b,
                                                 pk16x2 c, pk16x2 d) {
    intx4 v;
    v.x = __builtin_bit_cast(int, a);
    v.y = __builtin_bit_cast(int, b);
    v.z = __builtin_bit_cast(int, c);
    v.w = __builtin_bit_cast(int, d);
    return __builtin_bit_cast(half8, v);
}
static __device__ __forceinline__ half4 low_half(half8 v) {
    intx4 i = __builtin_bit_cast(intx4, v);
    intx2 r; r.x = i.x; r.y = i.y;
    return __builtin_bit_cast(half4, r);
}

// Split-f16 MFMA residual MLP.  hT lives in the MFMA D-fragment
// (m=quad*4+r, n=lane&15) == the next MFMA's B-fragment layout.
// Per residual layer: d = MFMA16(wc.lo, hhi, bias) then one K=32 correction
// MFMA with A' = column-interleaved [WThi | WTlo] (lds_wc) and
// B' = {hlo[0:4], hhi[0:4]} — merging Whi*hlo + Wlo*hhi into one MFMA.
// leaky(x) = 0.6x + 0.4|x| -> two FMAs (|x| is a free src modifier).
// hlo = h - (h & 0xFFFFE000)  ==  h - float(f16_rtz(h)) for normal h.
// 8 batch tiles per wave share all weight reads; 1024 blocks = 4 blocks/CU,
// all waves co-resident in a single round.
// LDS = 32K (wc) + 4K (w1hi) + 2K (bias) = 38912 B -> 4 blocks/CU.
__global__ __launch_bounds__(256, 4) void fractal_kernel(
    const float* __restrict__ z, const float* __restrict__ c,
    const float* __restrict__ W1, const float* __restrict__ b1,
    const float* __restrict__ Ws, const float* __restrict__ bs,
    const float* __restrict__ Wf, const float* __restrict__ bf,
    float* __restrict__ out, int B)
{
    __shared__ half8 lds_w1hi[4 * 64];       // layer-1 hi A frags
    __shared__ half8 lds_wc[NLAYERS * 64];   // correction A' frags (hi|lo)
    __shared__ floatx4 lds_bs[NLAYERS * 4];  // bias frags

    const int tid = threadIdx.x;
    const int lane = tid & 63;
    const int q = lane >> 4, col = lane & 15;

    // Stage W1^T hi fragments: A[m=col][k] = W1[k][col], k = t*32 + q*8 + j.
    {
        int t = tid >> 6, sl = tid & 63;
        int sq = sl >> 4, scol = sl & 15;
        half8 vh;
#pragma unroll
        for (int j = 0; j < 8; ++j) {
            int k = t * 32 + sq * 8 + j;
            float w = (k < INDIM) ? W1[k * H + scol] : 0.f;
            vh[j] = (_Float16)w;
        }
        lds_w1hi[tid] = vh;
    }
    // wc (K=32): A'[m][8q+j] = j<4 ? hi(Ws[l][4q+j][m]) : lo(Ws[l][4q+j-4][m])
    for (int idx = tid; idx < NLAYERS * 64; idx += 256) {
        int l = idx >> 6, sl = idx & 63;
        int sq = sl >> 4, scol = sl & 15;
        half8 vc;
#pragma unroll
        for (int j = 0; j < 4; ++j) {
            float w = Ws[l * H * H + (sq * 4 + j) * H + scol];
            _Float16 hi = (_Float16)w;
            vc[j] = hi;                              // slots j<4: hi (pairs hlo)
            vc[j + 4] = (_Float16)(w - (float)hi);   // slots j>=4: lo (pairs hhi)
        }
        lds_wc[idx] = vc;
    }
    for (int idx = tid; idx < NLAYERS * 4; idx += 256) {
        int l = idx >> 2, sq = idx & 3;
        floatx4 v;
#pragma unroll
        for (int j = 0; j < 4; ++j) v[j] = bs[l * H + sq * 4 + j];
        lds_bs[idx] = v;
    }

    // Layer-1 LO fragments live in registers (own lane's fragment only).
    half8 w1lo[4];
#pragma unroll
    for (int t = 0; t < 4; ++t) {
#pragma unroll
        for (int j = 0; j < 8; ++j) {
            int k = t * 32 + q * 8 + j;
            float w = (k < INDIM) ? W1[k * H + col] : 0.f;
            _Float16 hi = (_Float16)w;
            w1lo[t][j] = (_Float16)(w - (float)hi);
        }
    }
    __syncthreads();

    const int wave = (blockIdx.x * 256 + tid) >> 6;
    const int nwaves = (gridDim.x * 256) >> 6;   // 4096
    const int stride16 = nwaves * 16;            // batch stride between tiles

    constexpr float C_HI = 0.15915494309189535f;                        // fl(1/2pi)
    constexpr float C_LO = (float)(0.15915494309189535 - (double)C_HI); // residual

    const floatx2* z2 = (const floatx2*)z;
    const floatx2* c2 = (const floatx2*)c;
    const floatx4 bias1 = *(const floatx4*)(b1 + q * 4);
    const floatx4 wf4 = *(const floatx4*)(Wf + q * 4);
    const float bff = bf[0];

    const int n0 = wave * 16 + col;
    float h[8][4];   // h[i][r]: master fp32 hidden state for tile i

    // ---- Layer 1: positional encoding + Dense(124->16), 2 groups of 4 ----
#pragma unroll
    for (int g = 0; g < 2; ++g) {
        float yh[4][4], yl[4][4];   // [tile-in-group][dim]
#pragma unroll
        for (int u = 0; u < 4; ++u) {
            const int n = n0 + (g * 4 + u) * stride16;
            floatx2 zz = z2[n], cc = c2[n];
            float xv[4] = {zz.x, zz.y, cc.x, cc.y};
            // two-float x/(2pi): x*2^i exact in fp32, so frac((yh+yl)*2^i)
            // gives an accurate phase for sin(x*2^i) without Payne-Hanek.
#pragma unroll
            for (int d = 0; d < 4; ++d) {
                yh[u][d] = xv[d] * C_HI;
                yl[u][d] = __builtin_fmaf(xv[d], C_HI, -yh[u][d]) + xv[d] * C_LO;
            }
            // raw features x_d (t=0, cos slots, q==0) need xv later; stash in
            // yl-recoverable form?  Simpler: recompute from yh: x = yh / C_HI
            // is inexact — instead keep xv in h[] temporarily.
#pragma unroll
            for (int r = 0; r < 4; ++r) h[g * 4 + u][r] = xv[r];
        }
        floatx4 acc[4] = {bias1, bias1, bias1, bias1};
#pragma unroll
        for (int t = 0; t < 4; ++t) {
            // features k = t*32 + q*8 + j: j<4 -> cos(2^(t*4+q-1) x_d),
            // j>=4 -> sin(2^(t*4+q) x_d), d=j&3; t=0,q=0,j<4 -> raw x.
            // k=124..127 hit zeroed A columns — values harmless.
            const float sc_cos = __builtin_ldexpf(1.0f, t * 4 + q - 1);
            const float sc_sin = __builtin_ldexpf(1.0f, t * 4 + q);
            half8 ah = lds_w1hi[t * 64 + lane];   // shared across 4 tiles
            half8 al = w1lo[t];
#pragma unroll
            for (int u = 0; u < 4; ++u) {
                float fv[8];
#pragma unroll
                for (int j = 0; j < 8; ++j) {
                    const int d = j & 3;
                    const bool is_cos = (j < 4);
                    const float sc = is_cos ? sc_cos : sc_sin;
                    float fr = __builtin_amdgcn_fractf(yh[u][d] * sc);
                    fr = __builtin_fmaf(yl[u][d], sc, fr);
                    if (is_cos) fr += 0.25f;             // cos = sin(+1/4 rev)
                    fv[j] = __builtin_amdgcn_sinf(fr);
                    if (t == 0 && is_cos && q == 0) fv[j] = h[g * 4 + u][j];
                }
                half8 bh = mk_half8(__builtin_amdgcn_cvt_pkrtz(fv[0], fv[1]),
                                    __builtin_amdgcn_cvt_pkrtz(fv[2], fv[3]),
                                    __builtin_amdgcn_cvt_pkrtz(fv[4], fv[5]),
                                    __builtin_amdgcn_cvt_pkrtz(fv[6], fv[7]));
                acc[u] = __builtin_amdgcn_mfma_f32_16x16x32_f16(ah, bh, acc[u], 0, 0, 0);
                acc[u] = __builtin_amdgcn_mfma_f32_16x16x32_f16(al, bh, acc[u], 0, 0, 0);
            }
        }
#pragma unroll
        for (int u = 0; u < 4; ++u)
#pragma unroll
            for (int r = 0; r < 4; ++r)
                h[g * 4 + u][r] = fmaxf(acc[u][r], 0.2f * acc[u][r]);
    }

    // ---- 32 residual layers, 8 tiles interleaved ----
#pragma unroll
    for (int l = 0; l < NLAYERS; ++l) {
        half8 wc = lds_wc[l * 64 + lane];
        half4 wh = low_half(wc);          // == hi(Ws^T) fragment, free extract
        floatx4 bias = lds_bs[l * 4 + q];

#pragma unroll
        for (int i = 0; i < 8; ++i) {
            // hi = f16_rtz(h); float(hi) == h & 0xFFFFE000 for normal h.
            half4 hhi = mk_half4(__builtin_amdgcn_cvt_pkrtz(h[i][0], h[i][1]),
                                 __builtin_amdgcn_cvt_pkrtz(h[i][2], h[i][3]));
            float lo[4];
#pragma unroll
            for (int r = 0; r < 4; ++r) {
                unsigned u = __builtin_bit_cast(unsigned, h[i][r]) & 0xFFFFE000u;
                lo[r] = h[i][r] - __builtin_bit_cast(float, u);
            }
            intx2 hbits = __builtin_bit_cast(intx2, hhi);
            half8 bp = mk_half8(__builtin_amdgcn_cvt_pkrtz(lo[0], lo[1]),
                                __builtin_amdgcn_cvt_pkrtz(lo[2], lo[3]),
                                __builtin_bit_cast(pk16x2, hbits.x),
                                __builtin_bit_cast(pk16x2, hbits.y));
            floatx4 d = __builtin_amdgcn_mfma_f32_16x16x16f16(wh, hhi, bias, 0, 0, 0);
            d = __builtin_amdgcn_mfma_f32_16x16x32_f16(wc, bp, d, 0, 0, 0);
#pragma unroll
            for (int r = 0; r < 4; ++r) {
                // h += leaky(d) = 0.6d + 0.4|d|
                h[i][r] = __builtin_fmaf(0.6f, d[r], h[i][r]);
                h[i][r] = __builtin_fmaf(0.4f, __builtin_fabsf(d[r]), h[i][r]);
            }
        }
    }

    // ---- Final Dense(16->1): column n spread over 4 quads ----
#pragma unroll
    for (int i = 0; i < 8; ++i) {
        float p = h[i][0] * wf4.x;
        p = __builtin_fmaf(h[i][1], wf4.y, p);
        p = __builtin_fmaf(h[i][2], wf4.z, p);
        p = __builtin_fmaf(h[i][3], wf4.w, p);
        p += __shfl_xor(p, 16, 64);
        p += __shfl_xor(p, 32, 64);
        if (q == 0) out[n0 + i * stride16] = p + bff;
    }
}

extern "C" void kernel_launch(void* const* d_in, const int* in_sizes, int n_in,
                              void* d_out, int out_size, void* d_ws, size_t ws_size,
                              hipStream_t stream) {
    const float* z  = (const float*)d_in[0];
    const float* c  = (const float*)d_in[1];
    const float* W1 = (const float*)d_in[2];
    const float* b1 = (const float*)d_in[3];
    const float* Ws = (const float*)d_in[4];
    const float* bs = (const float*)d_in[5];
    const float* Wf = (const float*)d_in[6];
    const float* bf = (const float*)d_in[7];
    const int B = in_sizes[0] / 2;  // z is (B,2)

    const int blocks = 1024;  // 4096 waves x 8 tiles x 16 = 524288 samples
    fractal_kernel<<<blocks, 256, 0, stream>>>(z, c, W1, b1, Ws, bs, Wf, bf,
                                               (float*)d_out, B);
}